// Round 3
// baseline (3831.039 us; speedup 1.0000x reference)
//
#include <hip/hip_runtime.h>
#include <hip/hip_bf16.h>

typedef unsigned short u16;
typedef short short8 __attribute__((ext_vector_type(8)));
typedef float f32x4 __attribute__((ext_vector_type(4)));

#define B_SZ 2048
#define T_SZ 32
#define E_SZ 1024
#define H_SZ 16
#define HS_SZ 64

// Static device intermediates: no reliance on ws_size.
__device__ __align__(16) u16 g_Wqt[H_SZ * HS_SZ * E_SZ];   // (H,HS,E) bf16
__device__ __align__(16) u16 g_Wkt[H_SZ * HS_SZ * E_SZ];
__device__ __align__(16) u16 g_Wvt[H_SZ * HS_SZ * E_SZ];
__device__ __align__(16) u16 g_Wpt[E_SZ * E_SZ];           // (j,e) = Wp^T bf16
__device__ __align__(16) u16 g_xb[(size_t)B_SZ * T_SZ * E_SZ];  // x in bf16
__device__ __align__(16) u16 g_O[(size_t)B_SZ * T_SZ * E_SZ];   // attn out bf16

__device__ __forceinline__ f32x4 mfma16x16x32(short8 a, short8 b, f32x4 c) {
    return __builtin_amdgcn_mfma_f32_16x16x32_bf16(a, b, c, 0, 0, 0);
}

__device__ __forceinline__ u16 f2bf(float f) {
    __hip_bfloat16 h = __float2bfloat16(f);
    return __builtin_bit_cast(u16, h);
}

// fp32 -> bf16 flat convert of x. grid = B*T*E/2048 blocks of 256, 8 elems/thread.
__global__ __launch_bounds__(256) void xconv_kernel(const float* __restrict__ x) {
    size_t i = ((size_t)blockIdx.x * 256 + threadIdx.x) * 8;
    short8 o;
    #pragma unroll
    for (int j = 0; j < 8; j++) o[j] = (short)f2bf(x[i + j]);
    *(short8*)(g_xb + i) = o;
}

// Wq/Wk/Wv (H,E,HS) fp32 -> (H,HS,E) bf16 transposed. grid=(3*H, E/64), block=256.
__global__ __launch_bounds__(256) void wconv_qkv_kernel(
    const float* __restrict__ Wq, const float* __restrict__ Wk,
    const float* __restrict__ Wv)
{
    __shared__ float tile[64][65];
    int which = blockIdx.x >> 4;
    int h = blockIdx.x & 15;
    int rt = blockIdx.y;   // e-tile
    const float* in = (which == 0 ? Wq : which == 1 ? Wk : Wv) + (size_t)h * E_SZ * HS_SZ;
    u16* out = (which == 0 ? g_Wqt : which == 1 ? g_Wkt : g_Wvt) + (size_t)h * HS_SZ * E_SZ;
    int t = threadIdx.x;
    #pragma unroll
    for (int i = 0; i < 16; i++) {
        int idx = t + i * 256;
        int r = idx >> 6, c = idx & 63;
        tile[r][c] = in[(size_t)(rt * 64 + r) * HS_SZ + c];
    }
    __syncthreads();
    #pragma unroll
    for (int i = 0; i < 16; i++) {
        int idx = t + i * 256;
        int r = idx >> 6, c = idx & 63;
        // out[d=r][e=rt*64+c] = in[e][d] = tile[c][r]
        out[(size_t)r * E_SZ + rt * 64 + c] = f2bf(tile[c][r]);
    }
}

// Wp (E,E) fp32 -> g_Wpt[j][e] = Wp[e][j] bf16. grid=(E/64, E/64), block=256.
__global__ __launch_bounds__(256) void wconv_p_kernel(const float* __restrict__ Wp) {
    __shared__ float tile[64][65];
    int rt = blockIdx.x, ct = blockIdx.y;
    int t = threadIdx.x;
    #pragma unroll
    for (int i = 0; i < 16; i++) {
        int idx = t + i * 256;
        int r = idx >> 6, c = idx & 63;
        tile[r][c] = Wp[(size_t)(rt * 64 + r) * E_SZ + ct * 64 + c];
    }
    __syncthreads();
    #pragma unroll
    for (int i = 0; i < 16; i++) {
        int idx = t + i * 256;
        int r = idx >> 6, c = idx & 63;
        // g_Wpt[j=ct*64+r][e=rt*64+c] = Wp[e][j] = tile[c][r]
        g_Wpt[(size_t)(ct * 64 + r) * E_SZ + rt * 64 + c] = f2bf(tile[c][r]);
    }
}

// One block per (b,h): q,k,v = x_b @ W*[h], causal softmax, O = att @ v.
__global__ __launch_bounds__(256) void attn_kernel() {
    __shared__ u16 Qs[32][72];     // [t][d]
    __shared__ u16 Ks[32][72];     // [s][d]
    __shared__ u16 Vt[64][40];     // [d][s]  (transposed for PV B-operand)
    __shared__ float Ss[32][33];   // scores fp32
    __shared__ u16 Ps[32][40];     // softmax probs bf16

    int blk = blockIdx.x;
    int b = blk >> 4, h = blk & 15;          // consecutive blocks share b
    int tid = threadIdx.x;
    int wave = tid >> 6, lane = tid & 63;
    int m = lane & 15, quad = lane >> 4;

    // Phase 1: Q,K,V = x_b (32x1024) @ W (1024x64). Wave w owns d-cols [16w,16w+16).
    const u16* xr0 = g_xb + ((size_t)b * T_SZ + m) * E_SZ;   // A rows 0-15
    const u16* xr1 = xr0 + (size_t)16 * E_SZ;                // A rows 16-31
    size_t wrow = ((size_t)h * HS_SZ + wave * 16 + m) * E_SZ;
    const u16* wq = g_Wqt + wrow;
    const u16* wk = g_Wkt + wrow;
    const u16* wv = g_Wvt + wrow;

    f32x4 aq0 = {}, aq1 = {}, ak0 = {}, ak1 = {}, av0 = {}, av1 = {};

    for (int k0 = 0; k0 < E_SZ; k0 += 32) {
        int ko = k0 + quad * 8;
        short8 a0 = *(const short8*)(xr0 + ko);
        short8 a1 = *(const short8*)(xr1 + ko);
        short8 bq = *(const short8*)(wq + ko);
        short8 bk = *(const short8*)(wk + ko);
        short8 bv = *(const short8*)(wv + ko);
        aq0 = mfma16x16x32(a0, bq, aq0);
        aq1 = mfma16x16x32(a1, bq, aq1);
        ak0 = mfma16x16x32(a0, bk, ak0);
        ak1 = mfma16x16x32(a1, bk, ak1);
        av0 = mfma16x16x32(a0, bv, av0);
        av1 = mfma16x16x32(a1, bv, av1);
    }

    // C/D layout: col(N) = lane&15, row(M) = quad*4 + reg  [m89/m91 verified]
    int col = wave * 16 + m;
    #pragma unroll
    for (int r = 0; r < 4; r++) {
        int row = quad * 4 + r;
        Qs[row][col]      = f2bf(aq0[r]);
        Qs[row + 16][col] = f2bf(aq1[r]);
        Ks[row][col]      = f2bf(ak0[r]);
        Ks[row + 16][col] = f2bf(ak1[r]);
        Vt[col][row]      = f2bf(av0[r]);
        Vt[col][row + 16] = f2bf(av1[r]);
    }
    __syncthreads();

    // Phase 2: S = Q K^T (32x32, K=64). Tile (0,1) fully masked -> 3 tiles, 3 waves.
    if (wave < 3) {
        int tr = (wave + 1) >> 1, tc = wave >> 1;  // w0:(0,0) w1:(1,0) w2:(1,1)
        f32x4 s = {};
        #pragma unroll
        for (int kc = 0; kc < 2; kc++) {
            short8 qa = *(const short8*)&Qs[tr * 16 + m][kc * 32 + quad * 8];
            short8 kb = *(const short8*)&Ks[tc * 16 + m][kc * 32 + quad * 8];
            s = mfma16x16x32(qa, kb, s);
        }
        #pragma unroll
        for (int r = 0; r < 4; r++)
            Ss[tr * 16 + quad * 4 + r][tc * 16 + m] = s[r];
    }
    __syncthreads();

    // Phase 3: causal softmax, one thread per row
    if (tid < 32) {
        int t = tid;
        float mx = -1e30f;
        for (int s = 0; s <= t; s++) {
            float v = Ss[t][s] * 0.125f;   // HS^-0.5
            Ss[t][s] = v;
            mx = fmaxf(mx, v);
        }
        float sum = 0.f;
        for (int s = 0; s <= t; s++) {
            float p = __expf(Ss[t][s] - mx);
            Ss[t][s] = p;
            sum += p;
        }
        float inv = 1.f / sum;
        for (int s = 0; s < 32; s++)
            Ps[t][s] = (s <= t) ? f2bf(Ss[t][s] * inv) : (u16)0;
    }
    __syncthreads();

    // Phase 4: O = P (32x32) @ V (32x64). K=32 -> single MFMA per 16x16 tile.
    short8 p0 = *(const short8*)&Ps[m][quad * 8];
    short8 p1 = *(const short8*)&Ps[16 + m][quad * 8];
    short8 vb = *(const short8*)&Vt[wave * 16 + m][quad * 8];
    f32x4 o0 = mfma16x16x32(p0, vb, f32x4{});
    f32x4 o1 = mfma16x16x32(p1, vb, f32x4{});

    u16* obase = g_O + (size_t)b * T_SZ * E_SZ + h * HS_SZ + wave * 16 + m;
    #pragma unroll
    for (int r = 0; r < 4; r++) {
        int row = quad * 4 + r;
        obase[(size_t)row * E_SZ]        = f2bf(o0[r]);
        obase[(size_t)(row + 16) * E_SZ] = f2bf(o1[r]);
    }
}

// out(fp32) = g_O (65536x1024 bf16) @ Wp + bp. 16 rows/block staged to LDS.
// grid = 4096 blocks of 256.
__global__ __launch_bounds__(256) void proj_kernel(
    float* __restrict__ out, const float* __restrict__ bp)
{
    __shared__ u16 As[16][1032];   // 16 rows x 1024 (+8 pad)
    int tid = threadIdx.x;
    int wave = tid >> 6, lane = tid & 63;
    int m = lane & 15, quad = lane >> 4;
    size_t r0 = (size_t)blockIdx.x * 16;

    #pragma unroll
    for (int i = 0; i < 8; i++) {
        int e = (i * 256 + tid) * 8;
        int row = e >> 10, col = e & 1023;
        *(short8*)&As[row][col] = *(const short8*)(g_O + (r0 + row) * E_SZ + col);
    }
    __syncthreads();

    // Wave w owns output cols {w*16 + jt*64 + m : jt in [0,16)}
    for (int jt = 0; jt < 16; jt++) {
        int j0 = wave * 16 + jt * 64;
        const u16* Wb = g_Wpt + (size_t)(j0 + m) * E_SZ;
        f32x4 acc = {};
        for (int k0 = 0; k0 < E_SZ; k0 += 32) {
            int ko = k0 + quad * 8;
            short8 bfr = *(const short8*)(Wb + ko);
            short8 afr = *(const short8*)&As[m][ko];
            acc = mfma16x16x32(afr, bfr, acc);
        }
        float bias = bp[j0 + m];
        #pragma unroll
        for (int r = 0; r < 4; r++) {
            int row = quad * 4 + r;
            out[(r0 + row) * E_SZ + (j0 + m)] = acc[r] + bias;
        }
    }
}

extern "C" void kernel_launch(void* const* d_in, const int* in_sizes, int n_in,
                              void* d_out, int out_size, void* d_ws, size_t ws_size,
                              hipStream_t stream) {
    const float* x  = (const float*)d_in[0];
    const float* Wq = (const float*)d_in[1];
    const float* Wk = (const float*)d_in[2];
    const float* Wv = (const float*)d_in[3];
    const float* Wp = (const float*)d_in[4];
    const float* bp = (const float*)d_in[5];
    float* out = (float*)d_out;

    xconv_kernel<<<dim3((B_SZ * T_SZ * E_SZ) / 2048), 256, 0, stream>>>(x);
    wconv_qkv_kernel<<<dim3(3 * H_SZ, E_SZ / 64), 256, 0, stream>>>(Wq, Wk, Wv);
    wconv_p_kernel<<<dim3(E_SZ / 64, E_SZ / 64), 256, 0, stream>>>(Wp);

    attn_kernel<<<dim3(B_SZ * H_SZ), 256, 0, stream>>>();
    proj_kernel<<<dim3((B_SZ * T_SZ) / 16), 256, 0, stream>>>(out, bp);
}